// Round 14
// baseline (221.520 us; speedup 1.0000x reference)
//
#include <hip/hip_runtime.h>
#include <hip/hip_bf16.h>
#include <cmath>

#define N_S    2048
#define C_CLS  100
#define K_CL   4
#define A_DIM  128
#define LDSROW 132   // padded row stride: breaks row-power-of-2 bank aliasing
#define NB     16    // GJ panel width
#define MAXPER 96    // max samples per class (mean 20.5; >15 sigma headroom)
#define WTPAD  101   // k_out transposed-W stride (reads conflict-free)
#define SPB    8     // samples per k_out block (256 blocks)

// ===========================================================================
// Blocked Gauss-Jordan of As (in LDS), returns logdet in wave 0's lanes.
// Round-13 change: (c)-loop columns remapped (4cp, 64+4cp) -> 16B lane
// stride -> 2-way banks (free) instead of 4-way at 32B stride.
// ===========================================================================
__device__ __forceinline__ float gj_invert_lds(
    float* As, float* Rbuf, float* DinvS, int tid)
{
    const int lane = tid & 63;
    const int wv   = tid >> 6;
    float logdet = 0.0f;                 // valid in wave 0 only

    for (int t = 0; t < 8; ++t) {
        const int p0 = NB * t;

        // (a) wave 0: invert 16x16 diagonal block in registers (shfl GJ)
        if (wv == 0) {
            const int r = lane >> 2, cg = lane & 3;
            float4 dv = *(const float4*)&As[(p0 + r) * LDSROW + p0 + 4 * cg];
            #pragma unroll
            for (int p = 0; p < NB; ++p) {
                const int sel = p & 3, pr4 = p >> 2;
                float te = (sel == 0) ? dv.x : (sel == 1) ? dv.y : (sel == 2) ? dv.z : dv.w;
                float piv = __shfl(te, (p << 2) | pr4, 64);
                float ip  = 1.0f / piv;
                logdet += __logf(piv);
                const int rowsrc = (p << 2) | cg;
                float4 prs;
                prs.x = __shfl(dv.x, rowsrc, 64) * ip;
                prs.y = __shfl(dv.y, rowsrc, 64) * ip;
                prs.z = __shfl(dv.z, rowsrc, 64) * ip;
                prs.w = __shfl(dv.w, rowsrc, 64) * ip;
                if (cg == pr4) (&prs.x)[sel] = ip;           // (p,p) -> 1/piv
                float f = __shfl(te, (lane & ~3) | pr4, 64); // my row's col-p value
                if (r == p) {
                    dv = prs;
                } else {
                    dv.x -= f * prs.x; dv.y -= f * prs.y;
                    dv.z -= f * prs.z; dv.w -= f * prs.w;
                    if (cg == pr4) (&dv.x)[sel] = -f * ip;   // col p: assign
                }
            }
            DinvS[r * 17 + 4 * cg + 0] = dv.x;
            DinvS[r * 17 + 4 * cg + 1] = dv.y;
            DinvS[r * 17 + 4 * cg + 2] = dv.z;
            DinvS[r * 17 + 4 * cg + 3] = dv.w;
        }
        __syncthreads();   // b1: Dinv ready

        // (b) Rnew = Dinv * A[P,:] into Rbuf; panel cols get Dinv itself.
        {
            const int rr = tid >> 5, j4c = tid & 31;
            float4 o;
            if ((j4c >> 2) == t) {
                const int cg = j4c & 3;
                o.x = DinvS[rr * 17 + 4 * cg + 0];
                o.y = DinvS[rr * 17 + 4 * cg + 1];
                o.z = DinvS[rr * 17 + 4 * cg + 2];
                o.w = DinvS[rr * 17 + 4 * cg + 3];
            } else {
                o.x = 0.f; o.y = 0.f; o.z = 0.f; o.w = 0.f;
                #pragma unroll 4
                for (int k = 0; k < NB; ++k) {
                    const float a = DinvS[rr * 17 + k];          // broadcast
                    const float4 s4 = *(const float4*)&As[(p0 + k) * LDSROW + 4 * j4c];
                    o.x += a * s4.x; o.y += a * s4.y; o.z += a * s4.z; o.w += a * s4.w;
                }
            }
            *(float4*)&Rbuf[rr * A_DIM + 4 * j4c] = o;
        }
        __syncthreads();   // b2: Rnew ready (As panel rows still OLD)

        // (c) rank-16 update of 112 non-panel rows: per thread 4 rows x 2
        // float4-cols at (4cp, 64+4cp). 16B lane stride -> 2-way banks (free).
        if (tid < 448) {
            const int rgi = tid >> 4;                 // 0..27 non-panel row group
            const int cp  = tid & 15;
            const int rga = (rgi < 4 * t) ? rgi : rgi + 4;
            const int row0 = 4 * rga;
            const int c0 = 4 * cp, c1 = 64 + 4 * cp;
            const bool pc0 = ((cp >> 2) == t);        // first col is panel (t<4)
            const bool pc1 = (((cp >> 2) + 4) == t);  // second col is panel (t>=4)
            float4 a00, a01, a10, a11, a20, a21, a30, a31;
            if (pc0) {
                a00 = a10 = a20 = a30 = (float4){0, 0, 0, 0};
            } else {
                a00 = *(const float4*)&As[(row0 + 0) * LDSROW + c0];
                a10 = *(const float4*)&As[(row0 + 1) * LDSROW + c0];
                a20 = *(const float4*)&As[(row0 + 2) * LDSROW + c0];
                a30 = *(const float4*)&As[(row0 + 3) * LDSROW + c0];
            }
            if (pc1) {
                a01 = a11 = a21 = a31 = (float4){0, 0, 0, 0};
            } else {
                a01 = *(const float4*)&As[(row0 + 0) * LDSROW + c1];
                a11 = *(const float4*)&As[(row0 + 1) * LDSROW + c1];
                a21 = *(const float4*)&As[(row0 + 2) * LDSROW + c1];
                a31 = *(const float4*)&As[(row0 + 3) * LDSROW + c1];
            }
            #pragma unroll 4
            for (int k = 0; k < NB; ++k) {
                const float4 r0 = *(const float4*)&Rbuf[k * A_DIM + c0];
                const float4 r1 = *(const float4*)&Rbuf[k * A_DIM + c1];
                const float f0 = As[(row0 + 0) * LDSROW + p0 + k];
                const float f1 = As[(row0 + 1) * LDSROW + p0 + k];
                const float f2 = As[(row0 + 2) * LDSROW + p0 + k];
                const float f3 = As[(row0 + 3) * LDSROW + p0 + k];
                a00.x -= f0 * r0.x; a00.y -= f0 * r0.y; a00.z -= f0 * r0.z; a00.w -= f0 * r0.w;
                a01.x -= f0 * r1.x; a01.y -= f0 * r1.y; a01.z -= f0 * r1.z; a01.w -= f0 * r1.w;
                a10.x -= f1 * r0.x; a10.y -= f1 * r0.y; a10.z -= f1 * r0.z; a10.w -= f1 * r0.w;
                a11.x -= f1 * r1.x; a11.y -= f1 * r1.y; a11.z -= f1 * r1.z; a11.w -= f1 * r1.w;
                a20.x -= f2 * r0.x; a20.y -= f2 * r0.y; a20.z -= f2 * r0.z; a20.w -= f2 * r0.w;
                a21.x -= f2 * r1.x; a21.y -= f2 * r1.y; a21.z -= f2 * r1.z; a21.w -= f2 * r1.w;
                a30.x -= f3 * r0.x; a30.y -= f3 * r0.y; a30.z -= f3 * r0.z; a30.w -= f3 * r0.w;
                a31.x -= f3 * r1.x; a31.y -= f3 * r1.y; a31.z -= f3 * r1.z; a31.w -= f3 * r1.w;
            }
            *(float4*)&As[(row0 + 0) * LDSROW + c0] = a00;
            *(float4*)&As[(row0 + 0) * LDSROW + c1] = a01;
            *(float4*)&As[(row0 + 1) * LDSROW + c0] = a10;
            *(float4*)&As[(row0 + 1) * LDSROW + c1] = a11;
            *(float4*)&As[(row0 + 2) * LDSROW + c0] = a20;
            *(float4*)&As[(row0 + 2) * LDSROW + c1] = a21;
            *(float4*)&As[(row0 + 3) * LDSROW + c0] = a30;
            *(float4*)&As[(row0 + 3) * LDSROW + c1] = a31;
        }
        // copyback Rbuf -> As panel rows (panel rows untouched by the update)
        {
            const int rr = tid >> 5, j4c = tid & 31;
            *(float4*)&As[(p0 + rr) * LDSROW + 4 * j4c] =
                *(const float4*)&Rbuf[rr * A_DIM + 4 * j4c];
        }
        __syncthreads();   // b3: panel done
    }
    return logdet;
}

// ---------------------------------------------------------------------------
// Kernel 1 (FUSED): stage sigma -> bucket scan -> gprep (W in LDS chunks,
// round-13: replaces the s_load sweep whose K$ misses cost ~40us) -> blocked
// GJ inversion -> batched score tail.
// ---------------------------------------------------------------------------
__global__ __launch_bounds__(512, 2) void k_fused(
    const float* __restrict__ sigma, const float* __restrict__ mu,
    const float* __restrict__ features, const int* __restrict__ labels,
    const float* __restrict__ weight, float* __restrict__ score,
    float* __restrict__ gdiag, float* __restrict__ gcol)
{
    __shared__ __align__(16) float As[A_DIM * LDSROW];          // 67.6 KB
    __shared__ __align__(16) float Scratch[NB * A_DIM + 16*33]; // Wchunk/Rbuf/Dbuf+Par
    __shared__ float DinvS[NB * 17];
    __shared__ float ldS;
    __shared__ int idxL[MAXPER];
    __shared__ int cntA;

    const int tid  = threadIdx.x;
    const int bid  = blockIdx.x;         // cl*K_CL + k
    const int cl   = bid >> 2;
    const int lane = tid & 63;
    const int wv   = tid >> 6;

    if (tid == 0) cntA = 0;

    // ---- stage sigma (coalesced b128) ----
    const float4* src = (const float4*)(sigma + (size_t)bid * A_DIM * A_DIM);
    for (int e4 = tid; e4 < A_DIM * 32; e4 += 512) {
        int i = e4 >> 5, j4 = e4 & 31;
        *(float4*)&As[i * LDSROW + 4 * j4] = src[e4];
    }
    __syncthreads();

    // ---- bucket scan (labels are L2-resident 8KB) ----
    for (int n = tid; n < N_S; n += 512) {
        if (labels[n] == cl) {
            int s = atomicAdd(&cntA, 1);
            if (s < MAXPER) idxL[s] = n;
        }
    }

    // ---- gprep on resident sigma: W staged in 16-class LDS chunks ----
    {
        const float wc0 = weight[cl * A_DIM + lane];
        const float wc1 = weight[cl * A_DIM + 64 + lane];
        const int cL0 = wv * 2, cL1 = wv * 2 + 1;    // 8 waves x 2 classes/chunk
        for (int ch = 0; ch < 7; ++ch) {
            const int cbase = ch * 16;
            __syncthreads();                          // prev chunk compute done
            {   // stage 16 W rows (clamped) into Scratch: one float4/thread
                const int r = tid >> 5, j4 = tid & 31;
                const int crow = min(cbase + r, C_CLS - 1);
                *(float4*)&Scratch[r * A_DIM + 4 * j4] =
                    ((const float4*)weight)[crow * 32 + j4];
            }
            __syncthreads();
            float h00 = 0.f, h10 = 0.f, h01 = 0.f, h11 = 0.f;
            #pragma unroll 2
            for (int i = 0; i < A_DIM; ++i) {
                const float s0 = As[i * LDSROW + lane];       // 2-way (free)
                const float s1 = As[i * LDSROW + 64 + lane];
                const float b0 = Scratch[cL0 * A_DIM + i];    // broadcast (free)
                const float b1 = Scratch[cL1 * A_DIM + i];
                h00 += b0 * s0; h10 += b0 * s1;
                h01 += b1 * s0; h11 += b1 * s1;
            }
            const int ca = cbase + cL0, cb = cbase + cL1;
            if (ca < C_CLS) {
                float pd = h00 * Scratch[cL0 * A_DIM + lane]
                         + h10 * Scratch[cL0 * A_DIM + 64 + lane];
                float pc = h00 * wc0 + h10 * wc1;
                #pragma unroll
                for (int off = 32; off; off >>= 1) {
                    pd += __shfl_xor(pd, off, 64);
                    pc += __shfl_xor(pc, off, 64);
                }
                if (lane == 0) {
                    gdiag[bid * C_CLS + ca] = pd;
                    gcol [bid * C_CLS + ca] = pc;
                }
            }
            if (cb < C_CLS) {
                float pd = h01 * Scratch[cL1 * A_DIM + lane]
                         + h11 * Scratch[cL1 * A_DIM + 64 + lane];
                float pc = h01 * wc0 + h11 * wc1;
                #pragma unroll
                for (int off = 32; off; off >>= 1) {
                    pd += __shfl_xor(pd, off, 64);
                    pc += __shfl_xor(pc, off, 64);
                }
                if (lane == 0) {
                    gdiag[bid * C_CLS + cb] = pd;
                    gcol [bid * C_CLS + cb] = pc;
                }
            }
        }
    }
    __syncthreads();   // gprep/scan done before GJ overwrites As/Scratch

    float logdet = gj_invert_lds(As, Scratch, DinvS, tid);
    if (tid == 0) ldS = logdet;
    __syncthreads();
    const float ld = ldS;
    const int cnt = min(cntA, MAXPER);
    // As = Sigma^{-1}

    // ---- batched per-sample quadratic form (unchanged round-10 tail) ----
    float* Dbuf = Scratch;                  // [16][128]
    float* Par  = Scratch + NB * A_DIM;     // [16][33] padded
    const int s16 = tid >> 5;               // sample slot 0..15
    const int fc  = tid & 31;               // float4 column 0..31
    const float4 muv = ((const float4*)mu)[bid * 32 + fc];

    for (int c0 = 0; c0 < cnt; c0 += 16) {
        const int m = cnt - c0 < 16 ? cnt - c0 : 16;
        if (s16 < m) {
            const int n = idxL[c0 + s16];
            const float4 f = ((const float4*)features)[n * 32 + fc];
            float4 dv;
            dv.x = f.x - muv.x; dv.y = f.y - muv.y;
            dv.z = f.z - muv.z; dv.w = f.w - muv.w;
            *(float4*)&Dbuf[s16 * A_DIM + 4 * fc] = dv;
        }
        __syncthreads();
        if (s16 < m) {
            float4 p = {0.f, 0.f, 0.f, 0.f};
            #pragma unroll 4
            for (int i = 0; i < A_DIM; ++i) {
                const float  d = Dbuf[s16 * A_DIM + i];                    // broadcast
                const float4 a = *(const float4*)&As[i * LDSROW + 4 * fc]; // row-contig
                p.x += d * a.x; p.y += d * a.y; p.z += d * a.z; p.w += d * a.w;
            }
            const float4 dj = *(const float4*)&Dbuf[s16 * A_DIM + 4 * fc];
            Par[s16 * 33 + fc] = p.x * dj.x + p.y * dj.y + p.z * dj.z + p.w * dj.w;
        }
        __syncthreads();
        if (tid < m) {
            const int n = idxL[c0 + tid];
            float q = 0.f;
            #pragma unroll
            for (int j = 0; j < 32; ++j) q += Par[tid * 33 + j];
            score[n * K_CL + (bid & 3)] = q + ld;
        }
        __syncthreads();
    }
}

// ---------------------------------------------------------------------------
// Kernel 3 (unchanged): 256 blocks x 8 samples, W transposed in LDS,
// per-block loss accumulation.
// ---------------------------------------------------------------------------
__global__ __launch_bounds__(256) void k_out(
    const float* __restrict__ features, const float* __restrict__ weight,
    const float* __restrict__ bias, const int* __restrict__ labels,
    const float* __restrict__ score, const float* __restrict__ gdiag,
    const float* __restrict__ gcol, const float* __restrict__ ratio_p,
    float* __restrict__ y, float* __restrict__ loss)
{
    __shared__ float Wt[A_DIM * WTPAD];     // 51.7 KB transposed W
    __shared__ float bs[C_CLS];
    __shared__ __align__(16) float xs[2][A_DIM];
    __shared__ float red[2][2], red2[2][2], acl_s[2], lsum;

    const int tid  = threadIdx.x;
    const int half = tid >> 7;              // which sample of the pair
    const int t    = tid & 127;

    for (int u = tid; u < C_CLS * 32; u += 256) {
        const int c = u >> 5, j4 = u & 31;
        const float4 w = ((const float4*)weight)[u];
        Wt[(4 * j4 + 0) * WTPAD + c] = w.x;
        Wt[(4 * j4 + 1) * WTPAD + c] = w.y;
        Wt[(4 * j4 + 2) * WTPAD + c] = w.z;
        Wt[(4 * j4 + 3) * WTPAD + c] = w.w;
    }
    if (tid < C_CLS) bs[tid] = bias[tid];
    if (tid == 0) lsum = 0.f;
    __syncthreads();

    const float ratio = *ratio_p;

    for (int p = 0; p < SPB; p += 2) {
        const int n = blockIdx.x * SPB + p + half;
        if (t < 32) ((float4*)xs[half])[t] = ((const float4*)features)[n * 32 + t];
        __syncthreads();

        const int cl = labels[n];
        float s0 = score[n * 4 + 0], s1 = score[n * 4 + 1];
        float s2 = score[n * 4 + 2], s3 = score[n * 4 + 3];
        int ks = 0; float bsv = s0;              // strict <: first-min == jnp first-max
        if (s1 < bsv) { bsv = s1; ks = 1; }
        if (s2 < bsv) { bsv = s2; ks = 2; }
        if (s3 < bsv) { bsv = s3; ks = 3; }

        const int base = (cl * 4 + ks) * C_CLS;
        const float gll = gdiag[base + cl];
        float aug = -INFINITY;
        if (t < C_CLS) {
            float acc = bs[t];
            #pragma unroll 4
            for (int j = 0; j < A_DIM; ++j)
                acc += xs[half][j] * Wt[j * WTPAD + t];   // broadcast x conflict-free
            y[(size_t)n * C_CLS + t] = acc;
            aug = acc + 0.5f * ratio * (gdiag[base + t] - 2.0f * gcol[base + t] + gll);
        }

        float m = aug;
        #pragma unroll
        for (int off = 32; off; off >>= 1) m = fmaxf(m, __shfl_xor(m, off, 64));
        if ((t & 63) == 0) red[half][t >> 6] = m;
        __syncthreads();
        m = fmaxf(red[half][0], red[half][1]);

        float e = (t < C_CLS) ? expf(aug - m) : 0.0f;
        #pragma unroll
        for (int off = 32; off; off >>= 1) e += __shfl_xor(e, off, 64);
        if ((t & 63) == 0) red2[half][t >> 6] = e;
        if (t == cl) acl_s[half] = aug;
        __syncthreads();

        if (t == 0) {
            float lp = acl_s[half] - m - logf(red2[half][0] + red2[half][1]);
            atomicAdd(&lsum, -lp);
        }
        __syncthreads();    // protect xs/red before next pair
    }
    if (tid == 0) atomicAdd(loss, lsum * (1.0f / (float)N_S));
}

// ---------------------------------------------------------------------------
extern "C" void kernel_launch(void* const* d_in, const int* in_sizes, int n_in,
                              void* d_out, int out_size, void* d_ws, size_t ws_size,
                              hipStream_t stream) {
    const float* features = (const float*)d_in[0];
    const float* weight   = (const float*)d_in[1];
    const float* bias     = (const float*)d_in[2];
    // d_in[3] = pi : unused (q is one-hot for any pi > 0; argmax unaffected)
    const float* mu       = (const float*)d_in[4];
    const float* sigma    = (const float*)d_in[5];
    const int*   labels   = (const int*)d_in[6];
    const float* ratio    = (const float*)d_in[7];

    float* out   = (float*)d_out;   // [0] = loss, [1..204800] = y
    float* yout  = out + 1;
    float* score = (float*)d_ws;                  // 8192 f32
    float* gdiag = score + N_S * K_CL;            // 40000 f32
    float* gcol  = gdiag + C_CLS * K_CL * C_CLS;  // 40000 f32

    hipMemsetAsync(d_out, 0, sizeof(float), stream);   // zero the loss accumulator

    k_fused<<<dim3(C_CLS * K_CL), dim3(512), 0, stream>>>(sigma, mu, features, labels,
                                                          weight, score, gdiag, gcol);
    k_out  <<<dim3(N_S / SPB),    dim3(256), 0, stream>>>(features, weight, bias, labels,
                                                          score, gdiag, gcol, ratio, yout, out);
}